// Round 8
// baseline (246.799 us; speedup 1.0000x reference)
//
#include <hip/hip_runtime.h>
#include <stdint.h>

typedef __bf16 bf16_t;
typedef __bf16 bf16x8 __attribute__((ext_vector_type(8)));
typedef __bf16 bf16x4 __attribute__((ext_vector_type(4)));
typedef float floatx4 __attribute__((ext_vector_type(4)));

__device__ __forceinline__ void async_copy16(const bf16_t* g, bf16_t* l) {
  __builtin_amdgcn_global_load_lds(
      (const __attribute__((address_space(1))) void*)g,
      (__attribute__((address_space(3))) void*)l, 16, 0, 0);
}

// ---------- converts / reduce ----------
struct CvtSeg { const float* s; bf16_t* d; long n; };
struct CvtArgs { CvtSeg seg[5]; };

__global__ void cvt_multi(CvtArgs a) {
  CvtSeg sg = a.seg[blockIdx.y];
#pragma unroll
  for (int it = 0; it < 4; it++) {
    long i = (((long)blockIdx.x + (long)it * 2048) * 256 + threadIdx.x) * 4;
    if (i < sg.n) {
      float4 f = *(const float4*)(sg.s + i);
      bf16x4 o;
      o[0] = (bf16_t)f.x; o[1] = (bf16_t)f.y; o[2] = (bf16_t)f.z; o[3] = (bf16_t)f.w;
      *(bf16x4*)(sg.d + i) = o;
    }
  }
}

__global__ void reduce2_cvt(const float* __restrict__ a, const float* __restrict__ b,
                            bf16_t* __restrict__ d, long n) {
  long i = (((long)blockIdx.x) * 256 + threadIdx.x) * 4;
  if (i < n) {
    float4 x = *(const float4*)(a + i);
    float4 y = *(const float4*)(b + i);
    bf16x4 o;
    o[0] = (bf16_t)(x.x + y.x); o[1] = (bf16_t)(x.y + y.y);
    o[2] = (bf16_t)(x.z + y.z); o[3] = (bf16_t)(x.w + y.w);
    *(bf16x4*)(d + i) = o;
  }
}

// ---------- GEMM core: 128x128 tile, BK=32, dbuf LDS, xor-swizzled staging ----------
__device__ __forceinline__ void gemm_core(
    const bf16_t* __restrict__ Ab, const bf16_t* __restrict__ Bb,
    int lda, int ldb, int nk, bf16_t* As, bf16_t* Bs,
    int m0, int n0, floatx4 (&acc)[4][4]) {
  const int tid  = threadIdx.x;
  const int lane = tid & 63;
  const int w    = tid >> 6;
  const int wr   = w >> 1, wc = w & 1;
  const int quad = lane >> 4, lm = lane & 15;
  const int ar = lane >> 2;
  const int ak = (((lane & 3) ^ ((ar >> 1) & 3))) * 8;
  const bf16_t* ag0 = Ab + (long)(m0 + w * 16 + ar) * lda + ak;
  const bf16_t* ag1 = ag0 + (long)64 * lda;
  const bf16_t* bg0 = Bb + (long)(n0 + w * 16 + ar) * ldb + ak;
  const bf16_t* bg1 = bg0 + (long)64 * ldb;
  const int swz = (lm >> 1) & 3;

  {
    bf16_t* la = As + w * 512;
    bf16_t* lb = Bs + w * 512;
    async_copy16(ag0, la);
    async_copy16(ag1, la + 2048);
    async_copy16(bg0, lb);
    async_copy16(bg1, lb + 2048);
  }
  for (int i = 0; i < nk; i++) {
    __syncthreads();
    if (i + 1 < nk) {
      const int buf = (i + 1) & 1;
      const int k0  = (i + 1) * 32;
      bf16_t* la = As + buf * 4096 + w * 512;
      bf16_t* lb = Bs + buf * 4096 + w * 512;
      async_copy16(ag0 + k0, la);
      async_copy16(ag1 + k0, la + 2048);
      async_copy16(bg0 + k0, lb);
      async_copy16(bg1 + k0, lb + 2048);
    }
    const bf16_t* Ar = As + (i & 1) * 4096;
    const bf16_t* Br = Bs + (i & 1) * 4096;
    bf16x8 afr[4], bfr[4];
#pragma unroll
    for (int r = 0; r < 4; r++)
      afr[r] = *(const bf16x8*)&Ar[(wr * 64 + r * 16 + lm) * 32 + (quad ^ swz) * 8];
#pragma unroll
    for (int c = 0; c < 4; c++)
      bfr[c] = *(const bf16x8*)&Br[(wc * 64 + c * 16 + lm) * 32 + (quad ^ swz) * 8];
#pragma unroll
    for (int r = 0; r < 4; r++)
#pragma unroll
      for (int c = 0; c < 4; c++)
        acc[r][c] = __builtin_amdgcn_mfma_f32_16x16x32_bf16(afr[r], bfr[c], acc[r][c], 0, 0, 0);
  }
}

// ---------- fused q / kT / vT: 128x128 tile, LDS dbuf (proven) ----------
__global__ __launch_bounds__(256, 2) void qkv3(
    const bf16_t* __restrict__ xb,
    const bf16_t* __restrict__ Wq, const bf16_t* __restrict__ Wk, const bf16_t* __restrict__ Wv,
    const float* __restrict__ bq, const float* __restrict__ bk, const float* __restrict__ bv,
    bf16_t* __restrict__ qout, bf16_t* __restrict__ kT, bf16_t* __restrict__ vT) {
  __shared__ bf16_t As[2 * 4096];
  __shared__ bf16_t Bsh[3][2 * 4096];
  const int L = blockIdx.x;
  const int V = (L & 7) * 64 + (L >> 3);
  const int batch = V >> 7;
  const int rr_   = V & 127;
  const int n0 = (rr_ & 7) * 128;
  const int m0 = (rr_ >> 3) * 128;

  const int tid = threadIdx.x, lane = tid & 63, w = tid >> 6;
  const int wr = w >> 1, wc = w & 1, quad = lane >> 4, lm = lane & 15;
  const int ar = lane >> 2;
  const int ak = (((lane & 3) ^ ((ar >> 1) & 3))) * 8;
  const int swz = (lm >> 1) & 3;

  const bf16_t* ag0 = xb + (long)batch * (2048L * 1024) + (long)(m0 + w * 16 + ar) * 1024 + ak;
  const bf16_t* ag1 = ag0 + 64L * 1024;
  const bf16_t* Wp[3] = {Wq, Wk, Wv};
  const bf16_t* bg0[3];
  const bf16_t* bg1[3];
#pragma unroll
  for (int p = 0; p < 3; p++) {
    bg0[p] = Wp[p] + (long)(n0 + w * 16 + ar) * 1024 + ak;
    bg1[p] = bg0[p] + 64L * 1024;
  }

  floatx4 acc[3][4][4];
#pragma unroll
  for (int p = 0; p < 3; p++)
#pragma unroll
    for (int r = 0; r < 4; r++)
#pragma unroll
      for (int c = 0; c < 4; c++)
        acc[p][r][c] = (floatx4){0.f, 0.f, 0.f, 0.f};

  {
    bf16_t* la = As + w * 512;
    async_copy16(ag0, la);
    async_copy16(ag1, la + 2048);
#pragma unroll
    for (int p = 0; p < 3; p++) {
      bf16_t* lb = Bsh[p] + w * 512;
      async_copy16(bg0[p], lb);
      async_copy16(bg1[p], lb + 2048);
    }
  }
  for (int i = 0; i < 32; i++) {
    __syncthreads();
    if (i + 1 < 32) {
      const int buf = (i + 1) & 1, k0 = (i + 1) * 32;
      bf16_t* la = As + buf * 4096 + w * 512;
      async_copy16(ag0 + k0, la);
      async_copy16(ag1 + k0, la + 2048);
#pragma unroll
      for (int p = 0; p < 3; p++) {
        bf16_t* lb = Bsh[p] + buf * 4096 + w * 512;
        async_copy16(bg0[p] + k0, lb);
        async_copy16(bg1[p] + k0, lb + 2048);
      }
    }
    const bf16_t* Ar = As + (i & 1) * 4096;
    bf16x8 afr[4];
#pragma unroll
    for (int r = 0; r < 4; r++)
      afr[r] = *(const bf16x8*)&Ar[(wr * 64 + r * 16 + lm) * 32 + (quad ^ swz) * 8];
#pragma unroll
    for (int p = 0; p < 3; p++) {
      const bf16_t* Br = Bsh[p] + (i & 1) * 4096;
      bf16x8 bfr[4];
#pragma unroll
      for (int c = 0; c < 4; c++)
        bfr[c] = *(const bf16x8*)&Br[(wc * 64 + c * 16 + lm) * 32 + (quad ^ swz) * 8];
#pragma unroll
      for (int r = 0; r < 4; r++)
#pragma unroll
        for (int c = 0; c < 4; c++)
          acc[p][r][c] = __builtin_amdgcn_mfma_f32_16x16x32_bf16(afr[r], bfr[c], acc[p][r][c], 0, 0, 0);
    }
  }

  const int rowBase = m0 + wr * 64, colBase = n0 + wc * 64;
  {
    bf16_t* C = qout + (long)batch * (2048L * 1024);
#pragma unroll
    for (int r = 0; r < 4; r++) {
      const int row = rowBase + r * 16 + quad * 4;
#pragma unroll
      for (int c = 0; c < 4; c++) {
        const int col = colBase + c * 16 + lm;
        const float bv_ = bq[col];
#pragma unroll
        for (int i = 0; i < 4; i++)
          C[(long)(row + i) * 1024 + col] = (bf16_t)(acc[0][r][c][i] + bv_);
      }
    }
  }
#pragma unroll
  for (int p = 1; p < 3; p++) {
    bf16_t* C = ((p == 1) ? kT : vT) + (long)batch * (1024L * 2048);
    const float* bias = (p == 1) ? bk : bv;
#pragma unroll
    for (int r = 0; r < 4; r++) {
      const int row = rowBase + r * 16 + quad * 4;
#pragma unroll
      for (int c = 0; c < 4; c++) {
        const int col = colBase + c * 16 + lm;
        const float bv_ = bias[col];
        bf16x4 pk;
#pragma unroll
        for (int i = 0; i < 4; i++) pk[i] = (bf16_t)(acc[p][r][c][i] + bv_);
        *(bf16x4*)(C + (long)col * 2048 + row) = pk;
      }
    }
  }
}

// ---------- Mt: split-K x2, combo = (batch, khalf) pinned to XCD ----------
// grid 512: xcd = L&7 -> combo; j = L>>3 (0..63) -> 8x8 tiles of 128x128.
__global__ __launch_bounds__(256) void mt_gemm(
    const bf16_t* __restrict__ kT, const bf16_t* __restrict__ vT,
    float* __restrict__ P0, float* __restrict__ P1) {
  __shared__ bf16_t As[8192], Bs[8192];
  const int L = blockIdx.x;
  const int combo = L & 7;
  const int batch = combo & 3, kch = combo >> 2;
  const int j = L >> 3;
  const int m0 = (j >> 3) * 128;
  const int n0 = (j & 7) * 128;
  const bf16_t* Ab = kT + (long)batch * (1024L * 2048) + kch * 1024;
  const bf16_t* Bb = vT + (long)batch * (1024L * 2048) + kch * 1024;

  floatx4 acc[4][4];
#pragma unroll
  for (int r = 0; r < 4; r++)
#pragma unroll
    for (int c = 0; c < 4; c++) acc[r][c] = (floatx4){0.f, 0.f, 0.f, 0.f};

  gemm_core(Ab, Bb, 2048, 2048, 32, As, Bs, m0, n0, acc);

  const int lane = threadIdx.x & 63, w = threadIdx.x >> 6;
  const int wr = w >> 1, wc = w & 1, quad = lane >> 4, lm = lane & 15;
  float* Cf = (kch == 0 ? P0 : P1) + (long)batch * (1024L * 1024);
#pragma unroll
  for (int r = 0; r < 4; r++) {
    const int row = m0 + wr * 64 + r * 16 + quad * 4;
#pragma unroll
    for (int c = 0; c < 4; c++) {
      const int col = n0 + wc * 64 + c * 16 + lm;
#pragma unroll
      for (int i = 0; i < 4; i++)
        Cf[(long)(row + i) * 1024 + col] = acc[r][c][i] * 0.125f;
    }
  }
}

// ---------- G = Wo @ MtT^T: combo = (batch, mhalf) ----------
// grid 256: xcd = L&7; j = L>>3 (0..31): mt = j>>3 (0..3), nt = j&7.
__global__ __launch_bounds__(256) void g_gemm(
    const bf16_t* __restrict__ Wo, const bf16_t* __restrict__ MtT,
    bf16_t* __restrict__ G) {
  __shared__ bf16_t As[8192], Bs[8192];
  const int L = blockIdx.x;
  const int combo = L & 7;
  const int batch = combo & 3, mh = combo >> 2;
  const int j = L >> 3;
  const int m0 = (mh * 4 + (j >> 3)) * 128;
  const int n0 = (j & 7) * 128;
  const bf16_t* Bb = MtT + (long)batch * (1024L * 1024);

  floatx4 acc[4][4];
#pragma unroll
  for (int r = 0; r < 4; r++)
#pragma unroll
    for (int c = 0; c < 4; c++) acc[r][c] = (floatx4){0.f, 0.f, 0.f, 0.f};

  gemm_core(Wo, Bb, 1024, 1024, 32, As, Bs, m0, n0, acc);

  const int lane = threadIdx.x & 63, w = threadIdx.x >> 6;
  const int wr = w >> 1, wc = w & 1, quad = lane >> 4, lm = lane & 15;
  bf16_t* Cb = G + (long)batch * (1024L * 1024);
#pragma unroll
  for (int r = 0; r < 4; r++) {
    const int row = m0 + wr * 64 + r * 16 + quad * 4;
#pragma unroll
    for (int c = 0; c < 4; c++) {
      const int col = n0 + wc * 64 + c * 16 + lm;
#pragma unroll
      for (int i = 0; i < 4; i++)
        Cb[(long)(row + i) * 1024 + col] = (bf16_t)acc[r][c][i];
    }
  }
}

// ---------- final = q @ G^T + bo: combo = (batch, mquarter), 2 combos/XCD same batch ----------
// grid 512: xcd = L&7; s = (L>>3)&1; j = L>>4 (0..31): mt = j>>3 (0..3), nt = j&7.
__global__ __launch_bounds__(256) void final_gemm(
    const bf16_t* __restrict__ q, const bf16_t* __restrict__ G,
    const float* __restrict__ bo, float* __restrict__ out) {
  __shared__ bf16_t As[8192], Bs[8192];
  const int L = blockIdx.x;
  const int combo = ((L >> 3) & 1) * 8 + (L & 7);   // 0..15
  const int batch = combo & 3, mq = combo >> 2;
  const int j = L >> 4;
  const int m0 = (mq * 4 + (j >> 3)) * 128;
  const int n0 = (j & 7) * 128;
  const bf16_t* Ab = q + (long)batch * (2048L * 1024);
  const bf16_t* Bb = G + (long)batch * (1024L * 1024);

  floatx4 acc[4][4];
#pragma unroll
  for (int r = 0; r < 4; r++)
#pragma unroll
    for (int c = 0; c < 4; c++) acc[r][c] = (floatx4){0.f, 0.f, 0.f, 0.f};

  gemm_core(Ab, Bb, 1024, 1024, 32, As, Bs, m0, n0, acc);

  const int lane = threadIdx.x & 63, w = threadIdx.x >> 6;
  const int wr = w >> 1, wc = w & 1, quad = lane >> 4, lm = lane & 15;
  float* Cf = out + (long)batch * (2048L * 1024);
#pragma unroll
  for (int r = 0; r < 4; r++) {
    const int row = m0 + wr * 64 + r * 16 + quad * 4;
#pragma unroll
    for (int c = 0; c < 4; c++) {
      const int col = n0 + wc * 64 + c * 16 + lm;
      const float bv_ = bo[col];
#pragma unroll
      for (int i = 0; i < 4; i++)
        Cf[(long)(row + i) * 1024 + col] = acc[r][c][i] + bv_;
    }
  }
}

extern "C" void kernel_launch(void* const* d_in, const int* in_sizes, int n_in,
                              void* d_out, int out_size, void* d_ws, size_t ws_size,
                              hipStream_t stream) {
  const float* x  = (const float*)d_in[0];
  const float* Wq = (const float*)d_in[1];
  const float* bq = (const float*)d_in[2];
  const float* Wk = (const float*)d_in[3];
  const float* bk = (const float*)d_in[4];
  const float* Wv = (const float*)d_in[5];
  const float* bv = (const float*)d_in[6];
  const float* Wo = (const float*)d_in[7];
  const float* bo = (const float*)d_in[8];
  float* out = (float*)d_out;

  const long NX = 8192L * 1024;      // 8M elems
  const long NW = 1024L * 1024;      // 1M elems
  const long NM = 4L * 1024 * 1024;  // 4M elems

  bf16_t* ws  = (bf16_t*)d_ws;
  bf16_t* xb  = ws;                  // 8M units
  bf16_t* Wqb = xb + NX;             // 1M
  bf16_t* Wkb = Wqb + NW;
  bf16_t* Wvb = Wkb + NW;
  bf16_t* Wob = Wvb + NW;
  bf16_t* qb  = Wob + NW;            // 8M
  bf16_t* kT  = qb + NX;             // 8M [B][E][S]
  bf16_t* vT  = kT + NX;             // 8M [B][E][S]
  float*  P1  = (float*)(vT + NX);   // 4M floats (8M units)
  bf16_t* MtTb = vT + NX + NX;       // 4M units
  float*  P0  = (float*)xb;          // 4M floats, overlays xb (dead after qkv3)
  bf16_t* Gb  = xb;                  // overlays P0 (dead after reduce)

  CvtArgs ca;
  ca.seg[0] = {x,  xb,  NX};
  ca.seg[1] = {Wq, Wqb, NW};
  ca.seg[2] = {Wk, Wkb, NW};
  ca.seg[3] = {Wv, Wvb, NW};
  ca.seg[4] = {Wo, Wob, NW};
  cvt_multi<<<dim3(2048, 5), 256, 0, stream>>>(ca);

  qkv3<<<dim3(512), 256, 0, stream>>>(xb, Wqb, Wkb, Wvb, bq, bk, bv, qb, kT, vT);

  // MtT partials: combo (batch,khalf) per XCD, 4 MB slice fits L2
  mt_gemm<<<dim3(512), 256, 0, stream>>>(kT, vT, P0, P1);

  reduce2_cvt<<<dim3(NM / 1024), 256, 0, stream>>>(P0, P1, MtTb, NM);

  // G = Wo @ Mt  (stored as G[i,f]); combo (batch, mhalf)
  g_gemm<<<dim3(256), 256, 0, stream>>>(Wob, MtTb, Gb);

  // out = q @ G^T + bo; combo (batch, mquarter)
  final_gemm<<<dim3(512), 256, 0, stream>>>(qb, Gb, bo, out);
}